// Round 6
// baseline (313.993 us; speedup 1.0000x reference)
//
#include <hip/hip_runtime.h>
#include <hip/hip_bf16.h>

#define B_  4
#define T_  2048
#define C_  1024
#define NH_ 16
#define D_  64
#define BH_ (B_*NH_)   // 64
#define M_  (B_*T_)    // 8192

typedef __attribute__((ext_vector_type(8))) short short8;
typedef __attribute__((ext_vector_type(4))) short short4v;
typedef __attribute__((ext_vector_type(4))) float f32x4;

#define SC2 0.18033688011112043f   // (1/sqrt(64)) * log2(e)

__device__ __forceinline__ ushort f2bf(float f) {
    unsigned u = __float_as_uint(f);
    u += 0x7FFF + ((u >> 16) & 1);   // RNE
    return (ushort)(u >> 16);
}

__device__ __forceinline__ unsigned cvtpk(float lo, float hi) {
    unsigned r;
    asm("v_cvt_pk_bf16_f32 %0, %1, %2" : "=v"(r) : "v"(lo), "v"(hi));
    return r;
}

__device__ __forceinline__ void gload16(const void* g, void* lds) {
    __builtin_amdgcn_global_load_lds(
        (const __attribute__((address_space(1))) void*)g,
        (__attribute__((address_space(3))) void*)lds, 16, 0, 0);
}

// ---------------------------------------------------------------------------
// Prepass: fp32 -> bf16 convert (x) and transpose+convert (weights).
// ---------------------------------------------------------------------------
__global__ __launch_bounds__(256) void convert_x_kernel(
    const float* __restrict__ in, ushort* __restrict__ out, int n8)
{
    const int stride = gridDim.x * 256;
    for (int idx = blockIdx.x * 256 + threadIdx.x; idx < n8; idx += stride) {
        const float* p = in + (size_t)idx * 8;
        f32x4 a = *(const f32x4*)p;
        f32x4 b = *(const f32x4*)(p + 4);
        union { short8 v; ushort u[8]; } pk;
        #pragma unroll
        for (int j = 0; j < 4; ++j) { pk.u[j] = f2bf(a[j]); pk.u[4+j] = f2bf(b[j]); }
        *(short8*)&out[(size_t)idx * 8] = pk.v;
    }
}

// in [K][N] f32  ->  out [N][K] bf16
__global__ __launch_bounds__(256) void transpose_w_kernel(
    const float* __restrict__ in, ushort* __restrict__ out, int K, int N)
{
    __shared__ float t[64][65];
    const int tid = threadIdx.x;
    const int n0 = blockIdx.x * 64;
    const int k0 = blockIdx.y * 64;
    #pragma unroll
    for (int it = 0; it < 16; ++it) {
        const int kr = it*4 + (tid >> 6);
        t[kr][tid & 63] = in[(size_t)(k0 + kr) * N + n0 + (tid & 63)];
    }
    __syncthreads();
    const int nr8 = tid >> 3;          // 0..31
    const int kc0 = (tid & 7) * 8;
    #pragma unroll
    for (int j = 0; j < 2; ++j) {
        const int nr = j*32 + nr8;
        union { short8 v; ushort u[8]; } pk;
        #pragma unroll
        for (int e = 0; e < 8; ++e) pk.u[e] = f2bf(t[kc0 + e][nr]);
        *(short8*)&out[(size_t)(n0 + nr) * K + k0 + kc0] = pk.v;
    }
}

// ---------------------------------------------------------------------------
// 128x128-tile MFMA GEMM (m97 structure): BK=32, 4 waves each 64x64,
// global_load_lds width-16 staging, bf16 A [M][K] and Bt [N][K].
// MODE 0: scatter epilogue to Q (pre-scaled by SC2) / K / Vt with biases.
// MODE 1: out fp32 + b_proj.
// ---------------------------------------------------------------------------
template<int MODE>
__global__ __launch_bounds__(256) void gemm128_kernel(
    const ushort* __restrict__ A, const ushort* __restrict__ Bt,
    const float* __restrict__ b_attn, const float* __restrict__ bQv,
    const float* __restrict__ bKv,
    ushort* __restrict__ Qb, ushort* __restrict__ Kb, ushort* __restrict__ Vt,
    float* __restrict__ outp, const float* __restrict__ b_proj,
    int K, int N)
{
    __shared__ ushort As[128*32];   // 8 KB, row-major [row][32k], 64 B rows
    __shared__ ushort Bs[128*32];

    const int tid  = threadIdx.x;
    const int lane = tid & 63;
    const int w    = tid >> 6;
    const int wr   = w >> 1, wc = w & 1;
    const int l16  = lane & 15, lg = lane >> 4;
    const int m0   = blockIdx.x * 128, n0 = blockIdx.y * 128;

    const int srow = lane >> 2;          // 0..15
    const int scol = (lane & 3) * 8;     // k elems
    const ushort* aS = A  + (size_t)(m0 + w*32 + srow) * K + scol;
    const ushort* bS = Bt + (size_t)(n0 + w*32 + srow) * K + scol;
    ushort* aD0 = As + w*1024;
    ushort* aD1 = As + w*1024 + 512;
    ushort* bD0 = Bs + w*1024;
    ushort* bD1 = Bs + w*1024 + 512;

    f32x4 acc[4][4] = {};

    for (int k0 = 0; k0 < K; k0 += 32) {
        gload16(aS + k0,                 aD0);
        gload16(aS + (size_t)16*K + k0,  aD1);
        gload16(bS + k0,                 bD0);
        gload16(bS + (size_t)16*K + k0,  bD1);
        __syncthreads();

        short8 af[4], bf[4];
        #pragma unroll
        for (int i = 0; i < 4; ++i) {
            af[i] = *(const short8*)&As[(wr*64 + i*16 + l16)*32 + lg*8];
            bf[i] = *(const short8*)&Bs[(wc*64 + i*16 + l16)*32 + lg*8];
        }
        #pragma unroll
        for (int mi = 0; mi < 4; ++mi)
            #pragma unroll
            for (int ni = 0; ni < 4; ++ni)
                acc[mi][ni] = __builtin_amdgcn_mfma_f32_16x16x32_bf16(
                    af[mi], bf[ni], acc[mi][ni], 0, 0, 0);
        __syncthreads();
    }

    #pragma unroll
    for (int ni = 0; ni < 4; ++ni) {
        const int n = n0 + wc*64 + ni*16 + l16;
        if constexpr (MODE == 0) {
            const int sec = n >> 10;      // 0=Q 1=K 2=V
            const int nn  = n & 1023;
            const int h = nn >> 6, d = nn & 63;
            const float ba = b_attn[n];
            #pragma unroll
            for (int mi = 0; mi < 4; ++mi) {
                #pragma unroll
                for (int r = 0; r < 4; ++r) {
                    const int m = m0 + wr*64 + mi*16 + lg*4 + r;
                    const int b = m >> 11, t = m & 2047;
                    float v = acc[mi][ni][r] + ba;
                    if (sec == 0) {
                        v = (v + bQv[nn]) * SC2;  // fold softmax scale into Q
                        Qb[((size_t)(b*NH_ + h)*T_ + t)*D_ + d] = f2bf(v);
                    } else if (sec == 1) {
                        v += bKv[nn];
                        Kb[((size_t)(b*NH_ + h)*T_ + t)*D_ + d] = f2bf(v);
                    } else {
                        Vt[((size_t)(b*NH_ + h)*D_ + d)*T_ + t] = f2bf(v);
                    }
                }
            }
        } else {
            const float bp = b_proj[n];
            #pragma unroll
            for (int mi = 0; mi < 4; ++mi)
                #pragma unroll
                for (int r = 0; r < 4; ++r) {
                    const int m = m0 + wr*64 + mi*16 + lg*4 + r;
                    outp[(size_t)m * N + n] = acc[mi][ni][r] + bp;
                }
        }
    }
}

// ---------------------------------------------------------------------------
// Flash attention v6: 4-wave blocks, K/V double-buffered in LDS via
// global_load_lds (counted vmcnt, raw barriers), XOR-swizzled reads.
// ONE 128-q supertile per block -> grid 1024. Heavy-first + XCD-chunked.
// Softmax uses a STATIC max M0=16 folded into the QK MFMA C-init:
// p = exp2(s - 16) directly; no max tree, no alpha rescale (scores are
// statistically bounded: s2max ~ 7 << 144 overflow bound; 2^-16 cancels
// exactly in the final normalize).
// ---------------------------------------------------------------------------
__global__ __launch_bounds__(256, 4) void attn_kernel(
    const ushort* __restrict__ Qb, const ushort* __restrict__ Kb,
    const ushort* __restrict__ Vt, ushort* __restrict__ y)
{
    __shared__ char lds[2][16384];   // [buf][ K 8KB | V 8KB ]

    const int tid  = threadIdx.x;
    const int lane = tid & 63;
    const int w    = tid >> 6;
    const int l16  = lane & 15, lg = lane >> 4;
    const int bid  = blockIdx.x;
    const int xcd  = bid & 7;
    const int idx  = bid >> 3;                 // 0..127
    const int bh   = (xcd << 3) | (idx & 7);   // 8 bh per XCD
    const int p    = 15 - (idx >> 3);          // heavy supertiles first
    const int b    = bh >> 4, h = bh & 15;
    const size_t kvb = (size_t)bh * T_ * D_;
    const size_t vtb = (size_t)bh * D_ * T_;

    // staging decode (thread-constant): LDS[l] holds tile[r][c] where
    // l = (r*128 + c) ^ ((r&7)<<4)  =>  r = l>>7, c = (l&127)^((r&7)<<4)
    int srow[2], scol[2];
    #pragma unroll
    for (int i = 0; i < 2; ++i) {
        const int l = w*2048 + i*1024 + lane*16;
        const int r = l >> 7;
        const int c = (l & 127) ^ ((r & 7) << 4);
        srow[i] = r; scol[i] = c >> 1;         // elements
    }

    const f32x4 minit = {-16.f, -16.f, -16.f, -16.f};  // static-max C-init

    const int qB = p * 128;
    const int qw = qB + w * 32;                // wave's q base

    // Q fragments (B-slot), Q pre-scaled by SC2 at GEMM1
    short8 qf[2][2];
    #pragma unroll
    for (int g = 0; g < 2; ++g)
        #pragma unroll
        for (int c = 0; c < 2; ++c)
            qf[g][c] = *(const short8*)(Qb + kvb +
                        (size_t)(qw + g*16 + l16)*D_ + c*32 + lg*8);

    f32x4 o[2][4] = {};
    float lrow[2] = {0.f, 0.f};
    const int nt = 2*p + 2;

    // prologue: stage tile 0 into buf 0
    #pragma unroll
    for (int i = 0; i < 2; ++i) {
        gload16(Kb + kvb + (size_t)srow[i]*D_ + scol[i],
                &lds[0][w*2048 + i*1024]);
        gload16(Vt + vtb + (size_t)srow[i]*T_ + scol[i],
                &lds[0][8192 + w*2048 + i*1024]);
    }

    #pragma unroll 1
    for (int t = 0; t < nt; ++t) {
        const int kb = t * 64;
        if (t + 1 < nt) {
            char* Lb = lds[(t + 1) & 1];
            const int kb1 = kb + 64;
            #pragma unroll
            for (int i = 0; i < 2; ++i) {
                gload16(Kb + kvb + (size_t)(kb1 + srow[i])*D_ + scol[i],
                        Lb + w*2048 + i*1024);
                gload16(Vt + vtb + (size_t)srow[i]*T_ + kb1 + scol[i],
                        Lb + 8192 + w*2048 + i*1024);
            }
            asm volatile("s_waitcnt vmcnt(4)" ::: "memory");
        } else {
            asm volatile("s_waitcnt vmcnt(0)" ::: "memory");
        }
        __builtin_amdgcn_s_barrier();

        if (kb <= qw + 31) {               // wave-uniform work guard
            const char* Lk = lds[t & 1];
            const char* Lv = lds[t & 1] + 8192;

            // ---- S^T = K · Q^T (64 keys x 32 queries), C-init = -16 ----
            f32x4 s[2][4];
            #pragma unroll
            for (int t4 = 0; t4 < 4; ++t4) {
                const int r = t4*16 + l16;
                const int m = (r & 7) << 4;
                const short8 kc0 = *(const short8*)(Lk + r*128 + (( lg*16     ) ^ m));
                const short8 kc1 = *(const short8*)(Lk + r*128 + ((64 + lg*16 ) ^ m));
                s[0][t4] = __builtin_amdgcn_mfma_f32_16x16x32_bf16(kc0, qf[0][0], minit,    0, 0, 0);
                s[0][t4] = __builtin_amdgcn_mfma_f32_16x16x32_bf16(kc1, qf[0][1], s[0][t4], 0, 0, 0);
                s[1][t4] = __builtin_amdgcn_mfma_f32_16x16x32_bf16(kc0, qf[1][0], minit,    0, 0, 0);
                s[1][t4] = __builtin_amdgcn_mfma_f32_16x16x32_bf16(kc1, qf[1][1], s[1][t4], 0, 0, 0);
            }

            // ---- per-group softmax (no max pass) + pack + PV ----
            #pragma unroll
            for (int g = 0; g < 2; ++g) {
                const int qlo = qw + g*16;
                const bool full = (kb + 63 <= qlo);
                float x[4][4];
                float rs = 0.f;
                #pragma unroll
                for (int t4 = 0; t4 < 4; ++t4)
                    #pragma unroll
                    for (int r = 0; r < 4; ++r) {
                        float v = s[g][t4][r];
                        if (!full)
                            v = (kb + t4*16 + lg*4 + r <= qlo + l16) ? v : -1e30f;
                        const float pe = __builtin_amdgcn_exp2f(v);
                        x[t4][r] = pe;
                        rs += pe;
                    }
                rs += __shfl_xor(rs, 16, 64);
                rs += __shfl_xor(rs, 32, 64);
                lrow[g] += rs;

                union { unsigned u[4]; short8 v; } p0, p1;
                p0.u[0] = cvtpk(x[0][0], x[0][1]);
                p0.u[1] = cvtpk(x[0][2], x[0][3]);
                p0.u[2] = cvtpk(x[1][0], x[1][1]);
                p0.u[3] = cvtpk(x[1][2], x[1][3]);
                p1.u[0] = cvtpk(x[2][0], x[2][1]);
                p1.u[1] = cvtpk(x[2][2], x[2][3]);
                p1.u[2] = cvtpk(x[3][0], x[3][1]);
                p1.u[3] = cvtpk(x[3][2], x[3][3]);

                // ---- O^T += V^T · P^T (V from swizzled LDS) ----
                #pragma unroll
                for (int cb = 0; cb < 4; ++cb) {
                    const int d = cb*16 + l16;
                    const int mv = (d & 7) << 4;
                    const char* vb = Lv + d*128;
                    union { short8 v; short4v hh[2]; } v0, v1;
                    v0.hh[0] = *(const short4v*)(vb + ((lg*8     ) ^ mv));
                    v0.hh[1] = *(const short4v*)(vb + ((lg*8 + 32) ^ mv));
                    v1.hh[0] = *(const short4v*)(vb + ((lg*8 + 64) ^ mv));
                    v1.hh[1] = *(const short4v*)(vb + ((lg*8 + 96) ^ mv));
                    o[g][cb] = __builtin_amdgcn_mfma_f32_16x16x32_bf16(v0.v, p0.v, o[g][cb], 0, 0, 0);
                    o[g][cb] = __builtin_amdgcn_mfma_f32_16x16x32_bf16(v1.v, p1.v, o[g][cb], 0, 0, 0);
                }
            }
        }
        __builtin_amdgcn_s_barrier();
    }

    // ---- normalize + store y (bf16, [B][T][C]) ----
    #pragma unroll
    for (int g = 0; g < 2; ++g) {
        const float inv = 1.0f / lrow[g];
        const int q = qw + g*16 + l16;
        ushort* yr = y + ((size_t)b*T_ + q)*C_ + h*D_ + lg*4;
        #pragma unroll
        for (int cb = 0; cb < 4; ++cb) {
            union { unsigned u[2]; short4v v; } st;
            st.u[0] = cvtpk(o[g][cb][0]*inv, o[g][cb][1]*inv);
            st.u[1] = cvtpk(o[g][cb][2]*inv, o[g][cb][3]*inv);
            *(short4v*)(yr + cb*16) = st.v;
        }
    }
}

__global__ void copy_bq_kernel(const float* __restrict__ bQ, float* __restrict__ dst) {
    const int i = blockIdx.x * 256 + threadIdx.x;
    if (i < NH_ * D_) dst[i] = bQ[i];
}

extern "C" void kernel_launch(void* const* d_in, const int* in_sizes, int n_in,
                              void* d_out, int out_size, void* d_ws, size_t ws_size,
                              hipStream_t stream)
{
    const float* x      = (const float*)d_in[0];
    const float* W_attn = (const float*)d_in[1];
    const float* b_attn = (const float*)d_in[2];
    const float* W_proj = (const float*)d_in[3];
    const float* b_proj = (const float*)d_in[4];
    const float* bQ     = (const float*)d_in[5];
    const float* bK     = (const float*)d_in[6];
    float* out = (float*)d_out;

    const size_t HE = (size_t)BH_ * T_ * D_;   // 8M elems
    ushort* Qb = (ushort*)d_ws;
    ushort* Kb = Qb + HE;
    ushort* Vt = Kb + HE;
    ushort* y  = Vt + HE;
    ushort* Wpt = (ushort*)d_ws;               // aliases Qb (dead after attn)

    ushort* Xb  = (ushort*)d_out;              // scratch in d_out (dead before GEMM2)
    ushort* Wat = (ushort*)d_out + (size_t)M_ * C_;

    convert_x_kernel<<<2048, 256, 0, stream>>>(x, Xb, M_*C_/8);
    transpose_w_kernel<<<dim3(3*C_/64, C_/64), 256, 0, stream>>>(W_attn, Wat, C_, 3*C_);

    gemm128_kernel<0><<<dim3(M_/128, 3*C_/128), 256, 0, stream>>>(
        Xb, Wat, b_attn, bQ, bK, Qb, Kb, Vt, nullptr, nullptr, C_, 3*C_);

    attn_kernel<<<1024, 256, 0, stream>>>(Qb, Kb, Vt, y);

    transpose_w_kernel<<<dim3(C_/64, C_/64), 256, 0, stream>>>(W_proj, Wpt, C_, C_);

    gemm128_kernel<1><<<dim3(M_/128, C_/128), 256, 0, stream>>>(
        y, Wpt, nullptr, nullptr, nullptr, nullptr, nullptr, nullptr,
        out, b_proj, C_, C_);

    copy_bq_kernel<<<(NH_*D_ + 255)/256, 256, 0, stream>>>(
        bQ, out + (size_t)M_ * C_);
}

// Round 7
// 234.398 us; speedup vs baseline: 1.3396x; 1.3396x over previous
//
#include <hip/hip_runtime.h>
#include <hip/hip_bf16.h>

#define B_  4
#define T_  2048
#define C_  1024
#define NH_ 16
#define D_  64
#define BH_ (B_*NH_)   // 64
#define M_  (B_*T_)    // 8192

typedef __attribute__((ext_vector_type(8))) short short8;
typedef __attribute__((ext_vector_type(4))) short short4v;
typedef __attribute__((ext_vector_type(4))) float f32x4;

#define SC2 0.18033688011112043f   // (1/sqrt(64)) * log2(e)

__device__ __forceinline__ ushort f2bf(float f) {
    unsigned u = __float_as_uint(f);
    u += 0x7FFF + ((u >> 16) & 1);   // RNE
    return (ushort)(u >> 16);
}

__device__ __forceinline__ unsigned cvtpk(float lo, float hi) {
    unsigned r;
    asm("v_cvt_pk_bf16_f32 %0, %1, %2" : "=v"(r) : "v"(lo), "v"(hi));
    return r;
}

__device__ __forceinline__ void gload16(const void* g, void* lds) {
    __builtin_amdgcn_global_load_lds(
        (const __attribute__((address_space(1))) void*)g,
        (__attribute__((address_space(3))) void*)lds, 16, 0, 0);
}

// ---------------------------------------------------------------------------
// Prepass: fp32 -> bf16 convert (x) and transpose+convert (weights).
// ---------------------------------------------------------------------------
__global__ __launch_bounds__(256) void convert_x_kernel(
    const float* __restrict__ in, ushort* __restrict__ out, int n8)
{
    const int stride = gridDim.x * 256;
    for (int idx = blockIdx.x * 256 + threadIdx.x; idx < n8; idx += stride) {
        const float* p = in + (size_t)idx * 8;
        f32x4 a = *(const f32x4*)p;
        f32x4 b = *(const f32x4*)(p + 4);
        union { short8 v; ushort u[8]; } pk;
        #pragma unroll
        for (int j = 0; j < 4; ++j) { pk.u[j] = f2bf(a[j]); pk.u[4+j] = f2bf(b[j]); }
        *(short8*)&out[(size_t)idx * 8] = pk.v;
    }
}

// in [K][N] f32  ->  out [N][K] bf16
__global__ __launch_bounds__(256) void transpose_w_kernel(
    const float* __restrict__ in, ushort* __restrict__ out, int K, int N)
{
    __shared__ float t[64][65];
    const int tid = threadIdx.x;
    const int n0 = blockIdx.x * 64;
    const int k0 = blockIdx.y * 64;
    #pragma unroll
    for (int it = 0; it < 16; ++it) {
        const int kr = it*4 + (tid >> 6);
        t[kr][tid & 63] = in[(size_t)(k0 + kr) * N + n0 + (tid & 63)];
    }
    __syncthreads();
    const int nr8 = tid >> 3;          // 0..31
    const int kc0 = (tid & 7) * 8;
    #pragma unroll
    for (int j = 0; j < 2; ++j) {
        const int nr = j*32 + nr8;
        union { short8 v; ushort u[8]; } pk;
        #pragma unroll
        for (int e = 0; e < 8; ++e) pk.u[e] = f2bf(t[kc0 + e][nr]);
        *(short8*)&out[(size_t)(n0 + nr) * K + k0 + kc0] = pk.v;
    }
}

// ---------------------------------------------------------------------------
// 128x128-tile MFMA GEMM (m97 structure): BK=32, 4 waves each 64x64,
// global_load_lds width-16 staging, bf16 A [M][K] and Bt [N][K].
// MODE 0: scatter epilogue to Q (pre-scaled by SC2) / K / Vt with biases.
// MODE 1: out fp32 + b_proj.
// ---------------------------------------------------------------------------
template<int MODE>
__global__ __launch_bounds__(256) void gemm128_kernel(
    const ushort* __restrict__ A, const ushort* __restrict__ Bt,
    const float* __restrict__ b_attn, const float* __restrict__ bQv,
    const float* __restrict__ bKv,
    ushort* __restrict__ Qb, ushort* __restrict__ Kb, ushort* __restrict__ Vt,
    float* __restrict__ outp, const float* __restrict__ b_proj,
    int K, int N)
{
    __shared__ ushort As[128*32];   // 8 KB, row-major [row][32k], 64 B rows
    __shared__ ushort Bs[128*32];

    const int tid  = threadIdx.x;
    const int lane = tid & 63;
    const int w    = tid >> 6;
    const int wr   = w >> 1, wc = w & 1;
    const int l16  = lane & 15, lg = lane >> 4;
    const int m0   = blockIdx.x * 128, n0 = blockIdx.y * 128;

    const int srow = lane >> 2;          // 0..15
    const int scol = (lane & 3) * 8;     // k elems
    const ushort* aS = A  + (size_t)(m0 + w*32 + srow) * K + scol;
    const ushort* bS = Bt + (size_t)(n0 + w*32 + srow) * K + scol;
    ushort* aD0 = As + w*1024;
    ushort* aD1 = As + w*1024 + 512;
    ushort* bD0 = Bs + w*1024;
    ushort* bD1 = Bs + w*1024 + 512;

    f32x4 acc[4][4] = {};

    for (int k0 = 0; k0 < K; k0 += 32) {
        gload16(aS + k0,                 aD0);
        gload16(aS + (size_t)16*K + k0,  aD1);
        gload16(bS + k0,                 bD0);
        gload16(bS + (size_t)16*K + k0,  bD1);
        __syncthreads();

        short8 af[4], bf[4];
        #pragma unroll
        for (int i = 0; i < 4; ++i) {
            af[i] = *(const short8*)&As[(wr*64 + i*16 + l16)*32 + lg*8];
            bf[i] = *(const short8*)&Bs[(wc*64 + i*16 + l16)*32 + lg*8];
        }
        #pragma unroll
        for (int mi = 0; mi < 4; ++mi)
            #pragma unroll
            for (int ni = 0; ni < 4; ++ni)
                acc[mi][ni] = __builtin_amdgcn_mfma_f32_16x16x32_bf16(
                    af[mi], bf[ni], acc[mi][ni], 0, 0, 0);
        __syncthreads();
    }

    #pragma unroll
    for (int ni = 0; ni < 4; ++ni) {
        const int n = n0 + wc*64 + ni*16 + l16;
        if constexpr (MODE == 0) {
            const int sec = n >> 10;      // 0=Q 1=K 2=V
            const int nn  = n & 1023;
            const int h = nn >> 6, d = nn & 63;
            const float ba = b_attn[n];
            #pragma unroll
            for (int mi = 0; mi < 4; ++mi) {
                #pragma unroll
                for (int r = 0; r < 4; ++r) {
                    const int m = m0 + wr*64 + mi*16 + lg*4 + r;
                    const int b = m >> 11, t = m & 2047;
                    float v = acc[mi][ni][r] + ba;
                    if (sec == 0) {
                        v = (v + bQv[nn]) * SC2;  // fold softmax scale into Q
                        Qb[((size_t)(b*NH_ + h)*T_ + t)*D_ + d] = f2bf(v);
                    } else if (sec == 1) {
                        v += bKv[nn];
                        Kb[((size_t)(b*NH_ + h)*T_ + t)*D_ + d] = f2bf(v);
                    } else {
                        Vt[((size_t)(b*NH_ + h)*D_ + d)*T_ + t] = f2bf(v);
                    }
                }
            }
        } else {
            const float bp = b_proj[n];
            #pragma unroll
            for (int mi = 0; mi < 4; ++mi)
                #pragma unroll
                for (int r = 0; r < 4; ++r) {
                    const int m = m0 + wr*64 + mi*16 + lg*4 + r;
                    outp[(size_t)m * N + n] = acc[mi][ni][r] + bp;
                }
        }
    }
}

// ---------------------------------------------------------------------------
// Flash attention v7: round-5 inner code (online softmax, defer-rescale),
// but 64-q supertile per block (one 16-q group per wave) -> grid 2048,
// uniform p+1 tiles for ALL waves of a block, 5 blocks/CU resident
// (LDS 32KB x 5 = 160KB) + 3 queued for backfill. Heavy-first + XCD-chunked.
// K/V double-buffered in LDS via global_load_lds, XOR-swizzled reads.
// ---------------------------------------------------------------------------
__global__ __launch_bounds__(256, 5) void attn_kernel(
    const ushort* __restrict__ Qb, const ushort* __restrict__ Kb,
    const ushort* __restrict__ Vt, ushort* __restrict__ y)
{
    __shared__ char lds[2][16384];   // [buf][ K 8KB | V 8KB ]

    const int tid  = threadIdx.x;
    const int lane = tid & 63;
    const int w    = tid >> 6;
    const int l16  = lane & 15, lg = lane >> 4;
    const int bid  = blockIdx.x;
    const int xcd  = bid & 7;
    const int idx  = bid >> 3;                 // 0..255
    const int bh   = (xcd << 3) | (idx & 7);   // 8 bh per XCD
    const int p    = 31 - (idx >> 3);          // 0..31, heavy supertiles first
    const int b    = bh >> 4, h = bh & 15;
    const size_t kvb = (size_t)bh * T_ * D_;
    const size_t vtb = (size_t)bh * D_ * T_;

    // staging decode (thread-constant): LDS[l] holds tile[r][c] where
    // l = (r*128 + c) ^ ((r&7)<<4)  =>  r = l>>7, c = (l&127)^((r&7)<<4)
    int srow[2], scol[2];
    #pragma unroll
    for (int i = 0; i < 2; ++i) {
        const int l = w*2048 + i*1024 + lane*16;
        const int r = l >> 7;
        const int c = (l & 127) ^ ((r & 7) << 4);
        srow[i] = r; scol[i] = c >> 1;         // elements
    }

    const f32x4 z4 = {0.f, 0.f, 0.f, 0.f};

    const int qw = p * 64 + w * 16;            // wave's 16 q rows

    // Q fragments (B-slot), Q pre-scaled by SC2 at GEMM1
    short8 qf[2];
    #pragma unroll
    for (int c = 0; c < 2; ++c)
        qf[c] = *(const short8*)(Qb + kvb +
                    (size_t)(qw + l16)*D_ + c*32 + lg*8);

    f32x4 o[4] = {};
    float mrow = -1e30f;
    float lrow = 0.f;
    const int nt = p + 1;                      // same for all 4 waves

    // prologue: stage tile 0 into buf 0
    #pragma unroll
    for (int i = 0; i < 2; ++i) {
        gload16(Kb + kvb + (size_t)srow[i]*D_ + scol[i],
                &lds[0][w*2048 + i*1024]);
        gload16(Vt + vtb + (size_t)srow[i]*T_ + scol[i],
                &lds[0][8192 + w*2048 + i*1024]);
    }

    #pragma unroll 1
    for (int t = 0; t < nt; ++t) {
        const int kb = t * 64;
        if (t + 1 < nt) {
            char* Lb = lds[(t + 1) & 1];
            const int kb1 = kb + 64;
            #pragma unroll
            for (int i = 0; i < 2; ++i) {
                gload16(Kb + kvb + (size_t)(kb1 + srow[i])*D_ + scol[i],
                        Lb + w*2048 + i*1024);
                gload16(Vt + vtb + (size_t)srow[i]*T_ + kb1 + scol[i],
                        Lb + 8192 + w*2048 + i*1024);
            }
            asm volatile("s_waitcnt vmcnt(4)" ::: "memory");
        } else {
            asm volatile("s_waitcnt vmcnt(0)" ::: "memory");
        }
        __builtin_amdgcn_s_barrier();

        {
            const char* Lk = lds[t & 1];
            const char* Lv = lds[t & 1] + 8192;

            // ---- S^T = K · Q^T (64 keys x 16 queries) ----
            f32x4 s[4];
            #pragma unroll
            for (int t4 = 0; t4 < 4; ++t4) {
                const int r = t4*16 + l16;
                const int m = (r & 7) << 4;
                const short8 kc0 = *(const short8*)(Lk + r*128 + (( lg*16     ) ^ m));
                const short8 kc1 = *(const short8*)(Lk + r*128 + ((64 + lg*16 ) ^ m));
                s[t4] = __builtin_amdgcn_mfma_f32_16x16x32_bf16(kc0, qf[0], z4,    0, 0, 0);
                s[t4] = __builtin_amdgcn_mfma_f32_16x16x32_bf16(kc1, qf[1], s[t4], 0, 0, 0);
            }

            // ---- online softmax (16 q rows, lane's q = l16) ----
            const bool full = (kb + 63 <= qw);
            float x[4][4];
            #pragma unroll
            for (int t4 = 0; t4 < 4; ++t4)
                #pragma unroll
                for (int r = 0; r < 4; ++r) {
                    float v = s[t4][r];
                    if (!full)
                        v = (kb + t4*16 + lg*4 + r <= qw + l16) ? v : -1e30f;
                    x[t4][r] = v;
                }
            float vm0 = fmaxf(fmaxf(x[0][0], x[0][1]), fmaxf(x[0][2], x[0][3]));
            float vm1 = fmaxf(fmaxf(x[1][0], x[1][1]), fmaxf(x[1][2], x[1][3]));
            float vm2 = fmaxf(fmaxf(x[2][0], x[2][1]), fmaxf(x[2][2], x[2][3]));
            float vm3 = fmaxf(fmaxf(x[3][0], x[3][1]), fmaxf(x[3][2], x[3][3]));
            float vm  = fmaxf(fmaxf(vm0, vm1), fmaxf(vm2, vm3));
            vm = fmaxf(vm, __shfl_xor(vm, 16, 64));
            vm = fmaxf(vm, __shfl_xor(vm, 32, 64));
            const float mn = fmaxf(mrow, vm);
            float rs = 0.f;
            #pragma unroll
            for (int t4 = 0; t4 < 4; ++t4)
                #pragma unroll
                for (int r = 0; r < 4; ++r) {
                    const float pe = __builtin_amdgcn_exp2f(x[t4][r] - mn);
                    x[t4][r] = pe;
                    rs += pe;
                }
            rs += __shfl_xor(rs, 16, 64);
            rs += __shfl_xor(rs, 32, 64);
            if (__all(vm <= mrow)) {
                lrow += rs;                    // alpha == 1 exactly
            } else {
                const float al = __builtin_amdgcn_exp2f(mrow - mn);
                lrow = lrow*al + rs;
                #pragma unroll
                for (int cb = 0; cb < 4; ++cb)
                    #pragma unroll
                    for (int r = 0; r < 4; ++r)
                        o[cb][r] *= al;
            }
            mrow = mn;

            union { unsigned u[4]; short8 v; } p0, p1;
            p0.u[0] = cvtpk(x[0][0], x[0][1]);
            p0.u[1] = cvtpk(x[0][2], x[0][3]);
            p0.u[2] = cvtpk(x[1][0], x[1][1]);
            p0.u[3] = cvtpk(x[1][2], x[1][3]);
            p1.u[0] = cvtpk(x[2][0], x[2][1]);
            p1.u[1] = cvtpk(x[2][2], x[2][3]);
            p1.u[2] = cvtpk(x[3][0], x[3][1]);
            p1.u[3] = cvtpk(x[3][2], x[3][3]);

            // ---- O^T += V^T · P^T (V from swizzled LDS) ----
            #pragma unroll
            for (int cb = 0; cb < 4; ++cb) {
                const int d = cb*16 + l16;
                const int mv = (d & 7) << 4;
                const char* vb = Lv + d*128;
                union { short8 v; short4v hh[2]; } v0, v1;
                v0.hh[0] = *(const short4v*)(vb + ((lg*8     ) ^ mv));
                v0.hh[1] = *(const short4v*)(vb + ((lg*8 + 32) ^ mv));
                v1.hh[0] = *(const short4v*)(vb + ((lg*8 + 64) ^ mv));
                v1.hh[1] = *(const short4v*)(vb + ((lg*8 + 96) ^ mv));
                o[cb] = __builtin_amdgcn_mfma_f32_16x16x32_bf16(v0.v, p0.v, o[cb], 0, 0, 0);
                o[cb] = __builtin_amdgcn_mfma_f32_16x16x32_bf16(v1.v, p1.v, o[cb], 0, 0, 0);
            }
        }
        __builtin_amdgcn_s_barrier();
    }

    // ---- normalize + store y (bf16, [B][T][C]) ----
    {
        const float inv = 1.0f / lrow;
        const int q = qw + l16;
        ushort* yr = y + ((size_t)b*T_ + q)*C_ + h*D_ + lg*4;
        #pragma unroll
        for (int cb = 0; cb < 4; ++cb) {
            union { unsigned u[2]; short4v v; } st;
            st.u[0] = cvtpk(o[cb][0]*inv, o[cb][1]*inv);
            st.u[1] = cvtpk(o[cb][2]*inv, o[cb][3]*inv);
            *(short4v*)(yr + cb*16) = st.v;
        }
    }
}

__global__ void copy_bq_kernel(const float* __restrict__ bQ, float* __restrict__ dst) {
    const int i = blockIdx.x * 256 + threadIdx.x;
    if (i < NH_ * D_) dst[i] = bQ[i];
}

extern "C" void kernel_launch(void* const* d_in, const int* in_sizes, int n_in,
                              void* d_out, int out_size, void* d_ws, size_t ws_size,
                              hipStream_t stream)
{
    const float* x      = (const float*)d_in[0];
    const float* W_attn = (const float*)d_in[1];
    const float* b_attn = (const float*)d_in[2];
    const float* W_proj = (const float*)d_in[3];
    const float* b_proj = (const float*)d_in[4];
    const float* bQ     = (const float*)d_in[5];
    const float* bK     = (const float*)d_in[6];
    float* out = (float*)d_out;

    const size_t HE = (size_t)BH_ * T_ * D_;   // 8M elems
    ushort* Qb = (ushort*)d_ws;
    ushort* Kb = Qb + HE;
    ushort* Vt = Kb + HE;
    ushort* y  = Vt + HE;
    ushort* Wpt = (ushort*)d_ws;               // aliases Qb (dead after attn)

    ushort* Xb  = (ushort*)d_out;              // scratch in d_out (dead before GEMM2)
    ushort* Wat = (ushort*)d_out + (size_t)M_ * C_;

    convert_x_kernel<<<2048, 256, 0, stream>>>(x, Xb, M_*C_/8);
    transpose_w_kernel<<<dim3(3*C_/64, C_/64), 256, 0, stream>>>(W_attn, Wat, C_, 3*C_);

    gemm128_kernel<0><<<dim3(M_/128, 3*C_/128), 256, 0, stream>>>(
        Xb, Wat, b_attn, bQ, bK, Qb, Kb, Vt, nullptr, nullptr, C_, 3*C_);

    attn_kernel<<<2048, 256, 0, stream>>>(Qb, Kb, Vt, y);

    transpose_w_kernel<<<dim3(C_/64, C_/64), 256, 0, stream>>>(W_proj, Wpt, C_, C_);

    gemm128_kernel<1><<<dim3(M_/128, C_/128), 256, 0, stream>>>(
        y, Wpt, nullptr, nullptr, nullptr, nullptr, nullptr, nullptr,
        out, b_proj, C_, C_);

    copy_bq_kernel<<<(NH_*D_ + 255)/256, 256, 0, stream>>>(
        bQ, out + (size_t)M_ * C_);
}

// Round 8
// 210.599 us; speedup vs baseline: 1.4910x; 1.1130x over previous
//
#include <hip/hip_runtime.h>
#include <hip/hip_bf16.h>

#define B_  4
#define T_  2048
#define C_  1024
#define NH_ 16
#define D_  64
#define BH_ (B_*NH_)   // 64
#define M_  (B_*T_)    // 8192

typedef __attribute__((ext_vector_type(8))) short short8;
typedef __attribute__((ext_vector_type(4))) short short4v;
typedef __attribute__((ext_vector_type(4))) float f32x4;

#define SC2 0.18033688011112043f   // (1/sqrt(64)) * log2(e)

__device__ __forceinline__ ushort f2bf(float f) {
    unsigned u = __float_as_uint(f);
    u += 0x7FFF + ((u >> 16) & 1);   // RNE
    return (ushort)(u >> 16);
}

__device__ __forceinline__ unsigned cvtpk(float lo, float hi) {
    unsigned r;
    asm("v_cvt_pk_bf16_f32 %0, %1, %2" : "=v"(r) : "v"(lo), "v"(hi));
    return r;
}

__device__ __forceinline__ void gload16(const void* g, void* lds) {
    __builtin_amdgcn_global_load_lds(
        (const __attribute__((address_space(1))) void*)g,
        (__attribute__((address_space(3))) void*)lds, 16, 0, 0);
}

// ---------------------------------------------------------------------------
// Prepass: fp32 -> bf16 convert (x) and transpose+convert (weights).
// ---------------------------------------------------------------------------
__global__ __launch_bounds__(256) void convert_x_kernel(
    const float* __restrict__ in, ushort* __restrict__ out, int n8)
{
    const int stride = gridDim.x * 256;
    for (int idx = blockIdx.x * 256 + threadIdx.x; idx < n8; idx += stride) {
        const float* p = in + (size_t)idx * 8;
        f32x4 a = *(const f32x4*)p;
        f32x4 b = *(const f32x4*)(p + 4);
        union { short8 v; ushort u[8]; } pk;
        #pragma unroll
        for (int j = 0; j < 4; ++j) { pk.u[j] = f2bf(a[j]); pk.u[4+j] = f2bf(b[j]); }
        *(short8*)&out[(size_t)idx * 8] = pk.v;
    }
}

// in [K][N] f32  ->  out [N][K] bf16
__global__ __launch_bounds__(256) void transpose_w_kernel(
    const float* __restrict__ in, ushort* __restrict__ out, int K, int N)
{
    __shared__ float t[64][65];
    const int tid = threadIdx.x;
    const int n0 = blockIdx.x * 64;
    const int k0 = blockIdx.y * 64;
    #pragma unroll
    for (int it = 0; it < 16; ++it) {
        const int kr = it*4 + (tid >> 6);
        t[kr][tid & 63] = in[(size_t)(k0 + kr) * N + n0 + (tid & 63)];
    }
    __syncthreads();
    const int nr8 = tid >> 3;          // 0..31
    const int kc0 = (tid & 7) * 8;
    #pragma unroll
    for (int j = 0; j < 2; ++j) {
        const int nr = j*32 + nr8;
        union { short8 v; ushort u[8]; } pk;
        #pragma unroll
        for (int e = 0; e < 8; ++e) pk.u[e] = f2bf(t[kc0 + e][nr]);
        *(short8*)&out[(size_t)(n0 + nr) * K + k0 + kc0] = pk.v;
    }
}

// ---------------------------------------------------------------------------
// 128x128-tile MFMA GEMM, BK=32, 4 waves each 64x64, global_load_lds
// width-16 staging, DOUBLE-BUFFERED LDS (T3 2-phase): issue next tile's
// loads BEFORE computing current tile; the single __syncthreads per step
// (vmcnt(0)+lgkmcnt(0)+barrier) drains them after MFMA, so HBM latency
// hides under compute.
// MODE 0: scatter epilogue to Q (pre-scaled by SC2) / K / Vt with biases.
// MODE 1: out fp32 + b_proj.
// ---------------------------------------------------------------------------
template<int MODE>
__global__ __launch_bounds__(256) void gemm128_kernel(
    const ushort* __restrict__ A, const ushort* __restrict__ Bt,
    const float* __restrict__ b_attn, const float* __restrict__ bQv,
    const float* __restrict__ bKv,
    ushort* __restrict__ Qb, ushort* __restrict__ Kb, ushort* __restrict__ Vt,
    float* __restrict__ outp, const float* __restrict__ b_proj,
    int K, int N)
{
    __shared__ ushort As[2][128*32];   // 8 KB per buf, [row][32k], 64 B rows
    __shared__ ushort Bs[2][128*32];

    const int tid  = threadIdx.x;
    const int lane = tid & 63;
    const int w    = tid >> 6;
    const int wr   = w >> 1, wc = w & 1;
    const int l16  = lane & 15, lg = lane >> 4;
    const int m0   = blockIdx.x * 128, n0 = blockIdx.y * 128;

    const int srow = lane >> 2;          // 0..15
    const int scol = (lane & 3) * 8;     // k elems
    const ushort* aS = A  + (size_t)(m0 + w*32 + srow) * K + scol;
    const ushort* bS = Bt + (size_t)(n0 + w*32 + srow) * K + scol;

    f32x4 acc[4][4] = {};

    // prologue: stage tile 0 into buf 0
    {
        gload16(aS,                As[0] + w*1024);
        gload16(aS + (size_t)16*K, As[0] + w*1024 + 512);
        gload16(bS,                Bs[0] + w*1024);
        gload16(bS + (size_t)16*K, Bs[0] + w*1024 + 512);
    }
    __syncthreads();

    int cur = 0;
    for (int k0 = 0; k0 < K; k0 += 32) {
        // issue next tile's loads into the other buffer (overlaps compute)
        if (k0 + 32 < K) {
            const int nx = cur ^ 1;
            const int kn = k0 + 32;
            gload16(aS + kn,                As[nx] + w*1024);
            gload16(aS + (size_t)16*K + kn, As[nx] + w*1024 + 512);
            gload16(bS + kn,                Bs[nx] + w*1024);
            gload16(bS + (size_t)16*K + kn, Bs[nx] + w*1024 + 512);
        }

        short8 af[4], bf[4];
        #pragma unroll
        for (int i = 0; i < 4; ++i) {
            af[i] = *(const short8*)&As[cur][(wr*64 + i*16 + l16)*32 + lg*8];
            bf[i] = *(const short8*)&Bs[cur][(wc*64 + i*16 + l16)*32 + lg*8];
        }
        #pragma unroll
        for (int mi = 0; mi < 4; ++mi)
            #pragma unroll
            for (int ni = 0; ni < 4; ++ni)
                acc[mi][ni] = __builtin_amdgcn_mfma_f32_16x16x32_bf16(
                    af[mi], bf[ni], acc[mi][ni], 0, 0, 0);

        __syncthreads();   // vmcnt(0)+lgkmcnt(0)+barrier: next buf ready
        cur ^= 1;
    }

    #pragma unroll
    for (int ni = 0; ni < 4; ++ni) {
        const int n = n0 + wc*64 + ni*16 + l16;
        if constexpr (MODE == 0) {
            const int sec = n >> 10;      // 0=Q 1=K 2=V
            const int nn  = n & 1023;
            const int h = nn >> 6, d = nn & 63;
            const float ba = b_attn[n];
            #pragma unroll
            for (int mi = 0; mi < 4; ++mi) {
                #pragma unroll
                for (int r = 0; r < 4; ++r) {
                    const int m = m0 + wr*64 + mi*16 + lg*4 + r;
                    const int b = m >> 11, t = m & 2047;
                    float v = acc[mi][ni][r] + ba;
                    if (sec == 0) {
                        v = (v + bQv[nn]) * SC2;  // fold softmax scale into Q
                        Qb[((size_t)(b*NH_ + h)*T_ + t)*D_ + d] = f2bf(v);
                    } else if (sec == 1) {
                        v += bKv[nn];
                        Kb[((size_t)(b*NH_ + h)*T_ + t)*D_ + d] = f2bf(v);
                    } else {
                        Vt[((size_t)(b*NH_ + h)*D_ + d)*T_ + t] = f2bf(v);
                    }
                }
            }
        } else {
            const float bp = b_proj[n];
            #pragma unroll
            for (int mi = 0; mi < 4; ++mi)
                #pragma unroll
                for (int r = 0; r < 4; ++r) {
                    const int m = m0 + wr*64 + mi*16 + lg*4 + r;
                    outp[(size_t)m * N + n] = acc[mi][ni][r] + bp;
                }
        }
    }
}

// ---------------------------------------------------------------------------
// Flash attention v7: round-5 inner code (online softmax, defer-rescale),
// 64-q supertile per block (one 16-q group per wave) -> grid 2048,
// uniform p+1 tiles for ALL waves of a block, 5 blocks/CU resident.
// Heavy-first + XCD-chunked. K/V double-buffered in LDS via
// global_load_lds, XOR-swizzled reads.
// ---------------------------------------------------------------------------
__global__ __launch_bounds__(256, 5) void attn_kernel(
    const ushort* __restrict__ Qb, const ushort* __restrict__ Kb,
    const ushort* __restrict__ Vt, ushort* __restrict__ y)
{
    __shared__ char lds[2][16384];   // [buf][ K 8KB | V 8KB ]

    const int tid  = threadIdx.x;
    const int lane = tid & 63;
    const int w    = tid >> 6;
    const int l16  = lane & 15, lg = lane >> 4;
    const int bid  = blockIdx.x;
    const int xcd  = bid & 7;
    const int idx  = bid >> 3;                 // 0..255
    const int bh   = (xcd << 3) | (idx & 7);   // 8 bh per XCD
    const int p    = 31 - (idx >> 3);          // 0..31, heavy supertiles first
    const int b    = bh >> 4, h = bh & 15;
    const size_t kvb = (size_t)bh * T_ * D_;
    const size_t vtb = (size_t)bh * D_ * T_;

    // staging decode (thread-constant): LDS[l] holds tile[r][c] where
    // l = (r*128 + c) ^ ((r&7)<<4)  =>  r = l>>7, c = (l&127)^((r&7)<<4)
    int srow[2], scol[2];
    #pragma unroll
    for (int i = 0; i < 2; ++i) {
        const int l = w*2048 + i*1024 + lane*16;
        const int r = l >> 7;
        const int c = (l & 127) ^ ((r & 7) << 4);
        srow[i] = r; scol[i] = c >> 1;         // elements
    }

    const f32x4 z4 = {0.f, 0.f, 0.f, 0.f};

    const int qw = p * 64 + w * 16;            // wave's 16 q rows

    // Q fragments (B-slot), Q pre-scaled by SC2 at GEMM1
    short8 qf[2];
    #pragma unroll
    for (int c = 0; c < 2; ++c)
        qf[c] = *(const short8*)(Qb + kvb +
                    (size_t)(qw + l16)*D_ + c*32 + lg*8);

    f32x4 o[4] = {};
    float mrow = -1e30f;
    float lrow = 0.f;
    const int nt = p + 1;                      // same for all 4 waves

    // prologue: stage tile 0 into buf 0
    #pragma unroll
    for (int i = 0; i < 2; ++i) {
        gload16(Kb + kvb + (size_t)srow[i]*D_ + scol[i],
                &lds[0][w*2048 + i*1024]);
        gload16(Vt + vtb + (size_t)srow[i]*T_ + scol[i],
                &lds[0][8192 + w*2048 + i*1024]);
    }

    #pragma unroll 1
    for (int t = 0; t < nt; ++t) {
        const int kb = t * 64;
        if (t + 1 < nt) {
            char* Lb = lds[(t + 1) & 1];
            const int kb1 = kb + 64;
            #pragma unroll
            for (int i = 0; i < 2; ++i) {
                gload16(Kb + kvb + (size_t)(kb1 + srow[i])*D_ + scol[i],
                        Lb + w*2048 + i*1024);
                gload16(Vt + vtb + (size_t)srow[i]*T_ + kb1 + scol[i],
                        Lb + 8192 + w*2048 + i*1024);
            }
            asm volatile("s_waitcnt vmcnt(4)" ::: "memory");
        } else {
            asm volatile("s_waitcnt vmcnt(0)" ::: "memory");
        }
        __builtin_amdgcn_s_barrier();

        {
            const char* Lk = lds[t & 1];
            const char* Lv = lds[t & 1] + 8192;

            // ---- S^T = K · Q^T (64 keys x 16 queries) ----
            f32x4 s[4];
            #pragma unroll
            for (int t4 = 0; t4 < 4; ++t4) {
                const int r = t4*16 + l16;
                const int m = (r & 7) << 4;
                const short8 kc0 = *(const short8*)(Lk + r*128 + (( lg*16     ) ^ m));
                const short8 kc1 = *(const short8*)(Lk + r*128 + ((64 + lg*16 ) ^ m));
                s[t4] = __builtin_amdgcn_mfma_f32_16x16x32_bf16(kc0, qf[0], z4,    0, 0, 0);
                s[t4] = __builtin_amdgcn_mfma_f32_16x16x32_bf16(kc1, qf[1], s[t4], 0, 0, 0);
            }

            // ---- online softmax (16 q rows, lane's q = l16) ----
            const bool full = (kb + 63 <= qw);
            float x[4][4];
            #pragma unroll
            for (int t4 = 0; t4 < 4; ++t4)
                #pragma unroll
                for (int r = 0; r < 4; ++r) {
                    float v = s[t4][r];
                    if (!full)
                        v = (kb + t4*16 + lg*4 + r <= qw + l16) ? v : -1e30f;
                    x[t4][r] = v;
                }
            float vm0 = fmaxf(fmaxf(x[0][0], x[0][1]), fmaxf(x[0][2], x[0][3]));
            float vm1 = fmaxf(fmaxf(x[1][0], x[1][1]), fmaxf(x[1][2], x[1][3]));
            float vm2 = fmaxf(fmaxf(x[2][0], x[2][1]), fmaxf(x[2][2], x[2][3]));
            float vm3 = fmaxf(fmaxf(x[3][0], x[3][1]), fmaxf(x[3][2], x[3][3]));
            float vm  = fmaxf(fmaxf(vm0, vm1), fmaxf(vm2, vm3));
            vm = fmaxf(vm, __shfl_xor(vm, 16, 64));
            vm = fmaxf(vm, __shfl_xor(vm, 32, 64));
            const float mn = fmaxf(mrow, vm);
            float rs = 0.f;
            #pragma unroll
            for (int t4 = 0; t4 < 4; ++t4)
                #pragma unroll
                for (int r = 0; r < 4; ++r) {
                    const float pe = __builtin_amdgcn_exp2f(x[t4][r] - mn);
                    x[t4][r] = pe;
                    rs += pe;
                }
            rs += __shfl_xor(rs, 16, 64);
            rs += __shfl_xor(rs, 32, 64);
            if (__all(vm <= mrow)) {
                lrow += rs;                    // alpha == 1 exactly
            } else {
                const float al = __builtin_amdgcn_exp2f(mrow - mn);
                lrow = lrow*al + rs;
                #pragma unroll
                for (int cb = 0; cb < 4; ++cb)
                    #pragma unroll
                    for (int r = 0; r < 4; ++r)
                        o[cb][r] *= al;
            }
            mrow = mn;

            union { unsigned u[4]; short8 v; } p0, p1;
            p0.u[0] = cvtpk(x[0][0], x[0][1]);
            p0.u[1] = cvtpk(x[0][2], x[0][3]);
            p0.u[2] = cvtpk(x[1][0], x[1][1]);
            p0.u[3] = cvtpk(x[1][2], x[1][3]);
            p1.u[0] = cvtpk(x[2][0], x[2][1]);
            p1.u[1] = cvtpk(x[2][2], x[2][3]);
            p1.u[2] = cvtpk(x[3][0], x[3][1]);
            p1.u[3] = cvtpk(x[3][2], x[3][3]);

            // ---- O^T += V^T · P^T (V from swizzled LDS) ----
            #pragma unroll
            for (int cb = 0; cb < 4; ++cb) {
                const int d = cb*16 + l16;
                const int mv = (d & 7) << 4;
                const char* vb = Lv + d*128;
                union { short8 v; short4v hh[2]; } v0, v1;
                v0.hh[0] = *(const short4v*)(vb + ((lg*8     ) ^ mv));
                v0.hh[1] = *(const short4v*)(vb + ((lg*8 + 32) ^ mv));
                v1.hh[0] = *(const short4v*)(vb + ((lg*8 + 64) ^ mv));
                v1.hh[1] = *(const short4v*)(vb + ((lg*8 + 96) ^ mv));
                o[cb] = __builtin_amdgcn_mfma_f32_16x16x32_bf16(v0.v, p0.v, o[cb], 0, 0, 0);
                o[cb] = __builtin_amdgcn_mfma_f32_16x16x32_bf16(v1.v, p1.v, o[cb], 0, 0, 0);
            }
        }
        __builtin_amdgcn_s_barrier();
    }

    // ---- normalize + store y (bf16, [B][T][C]) ----
    {
        const float inv = 1.0f / lrow;
        const int q = qw + l16;
        ushort* yr = y + ((size_t)b*T_ + q)*C_ + h*D_ + lg*4;
        #pragma unroll
        for (int cb = 0; cb < 4; ++cb) {
            union { unsigned u[2]; short4v v; } st;
            st.u[0] = cvtpk(o[cb][0]*inv, o[cb][1]*inv);
            st.u[1] = cvtpk(o[cb][2]*inv, o[cb][3]*inv);
            *(short4v*)(yr + cb*16) = st.v;
        }
    }
}

__global__ void copy_bq_kernel(const float* __restrict__ bQ, float* __restrict__ dst) {
    const int i = blockIdx.x * 256 + threadIdx.x;
    if (i < NH_ * D_) dst[i] = bQ[i];
}

extern "C" void kernel_launch(void* const* d_in, const int* in_sizes, int n_in,
                              void* d_out, int out_size, void* d_ws, size_t ws_size,
                              hipStream_t stream)
{
    const float* x      = (const float*)d_in[0];
    const float* W_attn = (const float*)d_in[1];
    const float* b_attn = (const float*)d_in[2];
    const float* W_proj = (const float*)d_in[3];
    const float* b_proj = (const float*)d_in[4];
    const float* bQ     = (const float*)d_in[5];
    const float* bK     = (const float*)d_in[6];
    float* out = (float*)d_out;

    const size_t HE = (size_t)BH_ * T_ * D_;   // 8M elems
    ushort* Qb = (ushort*)d_ws;
    ushort* Kb = Qb + HE;
    ushort* Vt = Kb + HE;
    ushort* y  = Vt + HE;
    ushort* Wpt = (ushort*)d_ws;               // aliases Qb (dead after attn)

    ushort* Xb  = (ushort*)d_out;              // scratch in d_out (dead before GEMM2)
    ushort* Wat = (ushort*)d_out + (size_t)M_ * C_;

    convert_x_kernel<<<2048, 256, 0, stream>>>(x, Xb, M_*C_/8);
    transpose_w_kernel<<<dim3(3*C_/64, C_/64), 256, 0, stream>>>(W_attn, Wat, C_, 3*C_);

    gemm128_kernel<0><<<dim3(M_/128, 3*C_/128), 256, 0, stream>>>(
        Xb, Wat, b_attn, bQ, bK, Qb, Kb, Vt, nullptr, nullptr, C_, 3*C_);

    attn_kernel<<<2048, 256, 0, stream>>>(Qb, Kb, Vt, y);

    transpose_w_kernel<<<dim3(C_/64, C_/64), 256, 0, stream>>>(W_proj, Wpt, C_, C_);

    gemm128_kernel<1><<<dim3(M_/128, C_/128), 256, 0, stream>>>(
        y, Wpt, nullptr, nullptr, nullptr, nullptr, nullptr, nullptr,
        out, b_proj, C_, C_);

    copy_bq_kernel<<<(NH_*D_ + 255)/256, 256, 0, stream>>>(
        bQ, out + (size_t)M_ * C_);
}